// Round 16
// baseline (700.726 us; speedup 1.0000x reference)
//
#include <hip/hip_runtime.h>
#include <hip/hip_cooperative_groups.h>
#include <stdint.h>

namespace cg = cooperative_groups;

#define BATCH 4096

typedef float v16f __attribute__((ext_vector_type(16)));
typedef short v8s  __attribute__((ext_vector_type(8)));

__device__ __forceinline__ int sgn8(float v) {
    return (v > 0.f) ? 1 : ((v < 0.f) ? -1 : 0);
}

// ===========================================================================
// Shared device helpers (bit-identical between mega phases and fallback)
// ===========================================================================
__device__ __forceinline__ void finalize_dev(const double* __restrict__ part, int G,
                                             const float* __restrict__ g,
                                             const float* __restrict__ b,
                                             double inv_count, float* __restrict__ ssout,
                                             int c, int t, char* smem) {
    double s = 0.0, q = 0.0;
    for (int i = t; i < G; i += 256) {
        s += part[(size_t)c * G + i];
        q += part[(size_t)32 * G + (size_t)c * G + i];
    }
    #pragma unroll
    for (int o = 32; o > 0; o >>= 1) { s += __shfl_down(s, o); q += __shfl_down(q, o); }
    double* rs = (double*)smem;
    double* rq = rs + 4;
    int w = t >> 6, l = t & 63;
    if (l == 0) { rs[w] = s; rq[w] = q; }
    __syncthreads();
    if (t == 0) {
        s = rs[0] + rs[1] + rs[2] + rs[3];
        q = rq[0] + rq[1] + rq[2] + rq[3];
        double mean = s * inv_count;
        double var = q * inv_count - mean * mean;
        double sc = (double)g[c] / sqrt(var + 1e-5);
        ssout[c] = (float)sc;
        ssout[32 + c] = (float)((double)b[c] - mean * sc);
    }
    __syncthreads();
}

// ===========================================================================
// Cooperative mega-kernel: 512 blocks x 256 threads, launch_bounds(256,2)
// (<=256 VGPR -- trivially satisfiable; 32KB LDS -> occupancy >= 2/CU, so
// 512 blocks are co-resident). All per-thread math bit-identical to the
// fallback kernels below.
// ===========================================================================
__global__ __launch_bounds__(256, 2) void k_mega(
    const float* __restrict__ x,  const float* __restrict__ w0,
    const float* __restrict__ w1, const float* __restrict__ w2,
    const float* __restrict__ g0, const float* __restrict__ b0,
    const float* __restrict__ g1, const float* __restrict__ b1,
    const float* __restrict__ g2, const float* __restrict__ b2,
    const float* __restrict__ fw, const float* __restrict__ fb,
    uint16_t* __restrict__ w1f, uint16_t* __restrict__ w2f,
    float* __restrict__ ss, float* __restrict__ p1,
    float* __restrict__ hp1, float* __restrict__ p2,
    uint32_t* __restrict__ s0b, double* __restrict__ part0,
    double* __restrict__ part1, double* __restrict__ part2,
    float* __restrict__ hp0, float* __restrict__ outv)
{
    __shared__ __align__(16) char smem[32768];
    cg::grid_group grid = cg::this_grid();
    int t = threadIdx.x, blk = blockIdx.x;
    int lane = t & 63, wv = t >> 6;

    // ---- Phase A: signw (blocks 0..71) ----
    {
        int i = blk * 256 + t;
        if (i < 18432) {
            int ii = (i < 9216) ? i : i - 9216;
            const float* w = (i < 9216) ? w1 : w2;
            uint16_t* o = (i < 9216) ? w1f : w2f;
            int j = ii & 7, nn = (ii >> 3) & 31, q2 = (ii >> 8) & 1, kh = (ii >> 9) & 1, tp = ii >> 10;
            int cin = kh * 16 + q2 * 8 + j;
            float v = w[(nn * 32 + cin) * 9 + tp];
            o[ii] = (v > 0.f) ? 0x3F80 : ((v < 0.f) ? 0xBF80 : 0);
        }
    }

    // ---- Phase B: conv0 stats (8 images/block) ----
    {
        float* xs = (float*)smem;
        float* wl = xs + 960;
        double* rs = (double*)(smem + 5120);
        double* rq = rs + 448;
        int c = t & 31, py0 = t >> 5;
        for (int rep = 0; rep < 8; ++rep) {
            int n = blk + rep * 512;
            for (int i = t; i < 960; i += 256) xs[i] = 0.f;
            if (rep == 0) for (int i = t; i < 288; i += 256) wl[i] = w0[i];
            __syncthreads();
            for (int i = t; i < 784; i += 256) {
                int y = i / 28, xx = i - y * 28;
                xs[(y + 1) * 32 + xx + 1] = x[n * 784 + i];
            }
            __syncthreads();
            float wreg[9];
            #pragma unroll
            for (int i = 0; i < 9; ++i) wreg[i] = wl[c * 9 + i];
            const float4* X4 = (const float4*)xs;
            for (int py = py0; py < 14; py += 8) {
                float4 cur0 = X4[(2 * py + 0) * 8];
                float4 cur1 = X4[(2 * py + 1) * 8];
                float4 cur2 = X4[(2 * py + 2) * 8];
                float4 cur3 = X4[(2 * py + 3) * 8];
                double s = 0.0, q = 0.0;
                #pragma unroll
                for (int k = 0; k < 7; ++k) {
                    float4 n0 = X4[(2 * py + 0) * 8 + k + 1];
                    float4 n1 = X4[(2 * py + 1) * 8 + k + 1];
                    float4 n2 = X4[(2 * py + 2) * 8 + k + 1];
                    float4 n3 = X4[(2 * py + 3) * 8 + k + 1];
                    float a[4][6];
                    a[0][0] = cur0.x; a[0][1] = cur0.y; a[0][2] = cur0.z; a[0][3] = cur0.w; a[0][4] = n0.x; a[0][5] = n0.y;
                    a[1][0] = cur1.x; a[1][1] = cur1.y; a[1][2] = cur1.z; a[1][3] = cur1.w; a[1][4] = n1.x; a[1][5] = n1.y;
                    a[2][0] = cur2.x; a[2][1] = cur2.y; a[2][2] = cur2.z; a[2][3] = cur2.w; a[2][4] = n2.x; a[2][5] = n2.y;
                    a[3][0] = cur3.x; a[3][1] = cur3.y; a[3][2] = cur3.z; a[3][3] = cur3.w; a[3][4] = n3.x; a[3][5] = n3.y;
                    #pragma unroll
                    for (int e = 0; e < 2; ++e) {
                        int base = 2 * e;
                        float s00 = 0.f, s01 = 0.f, s10 = 0.f, s11 = 0.f;
                        #pragma unroll
                        for (int ky = 0; ky < 3; ++ky)
                        #pragma unroll
                        for (int kx = 0; kx < 3; ++kx) {
                            float w = wreg[ky * 3 + kx];
                            s00 = fmaf(a[ky][base + kx], w, s00);
                            s01 = fmaf(a[ky][base + kx + 1], w, s01);
                            s10 = fmaf(a[ky + 1][base + kx], w, s10);
                            s11 = fmaf(a[ky + 1][base + kx + 1], w, s11);
                        }
                        float m = fmaxf(fmaxf(s00, s01), fmaxf(s10, s11));
                        double v = (double)m;
                        s += v; q += v * v;
                    }
                    cur0 = n0; cur1 = n1; cur2 = n2; cur3 = n3;
                }
                rs[c * 14 + py] = s; rq[c * 14 + py] = q;
            }
            __syncthreads();
            if (t < 32) {
                double S = 0.0, Q = 0.0;
                #pragma unroll
                for (int i = 0; i < 14; ++i) { S += rs[t * 14 + i]; Q += rq[t * 14 + i]; }
                part0[(size_t)t * 4096 + n] = S;
                part0[(size_t)32 * 4096 + (size_t)t * 4096 + n] = Q;
            }
            __syncthreads();
        }
    }
    grid.sync();

    // ---- Phase C: finalize0 ----
    if (blk < 32) finalize_dev(part0, 4096, g0, b0, 1.0 / (4096.0 * 196.0), ss, blk, t, smem);
    grid.sync();

    // ---- Phase D: bn0r (8 images/block) ----
    {
        float* xs = (float*)smem;
        float* wl = xs + 960;
        float* P  = (float*)(smem + 5120);   // 196 x 33
        int c = t & 31, py0 = t >> 5;
        float scv = ss[c], shv = ss[32 + c];
        for (int rep = 0; rep < 8; ++rep) {
            int n = blk + rep * 512;
            for (int i = t; i < 960; i += 256) xs[i] = 0.f;
            if (rep == 0) for (int i = t; i < 288; i += 256) wl[i] = w0[i];
            __syncthreads();
            for (int i = t; i < 784; i += 256) {
                int y = i / 28, xx = i - y * 28;
                xs[(y + 1) * 32 + xx + 1] = x[n * 784 + i];
            }
            __syncthreads();
            float wreg[9];
            #pragma unroll
            for (int i = 0; i < 9; ++i) wreg[i] = wl[c * 9 + i];
            const float4* X4 = (const float4*)xs;
            for (int py = py0; py < 14; py += 8) {
                float4 cur0 = X4[(2 * py + 0) * 8];
                float4 cur1 = X4[(2 * py + 1) * 8];
                float4 cur2 = X4[(2 * py + 2) * 8];
                float4 cur3 = X4[(2 * py + 3) * 8];
                #pragma unroll
                for (int k = 0; k < 7; ++k) {
                    float4 n0 = X4[(2 * py + 0) * 8 + k + 1];
                    float4 n1 = X4[(2 * py + 1) * 8 + k + 1];
                    float4 n2 = X4[(2 * py + 2) * 8 + k + 1];
                    float4 n3 = X4[(2 * py + 3) * 8 + k + 1];
                    float a[4][6];
                    a[0][0] = cur0.x; a[0][1] = cur0.y; a[0][2] = cur0.z; a[0][3] = cur0.w; a[0][4] = n0.x; a[0][5] = n0.y;
                    a[1][0] = cur1.x; a[1][1] = cur1.y; a[1][2] = cur1.z; a[1][3] = cur1.w; a[1][4] = n1.x; a[1][5] = n1.y;
                    a[2][0] = cur2.x; a[2][1] = cur2.y; a[2][2] = cur2.z; a[2][3] = cur2.w; a[2][4] = n2.x; a[2][5] = n2.y;
                    a[3][0] = cur3.x; a[3][1] = cur3.y; a[3][2] = cur3.z; a[3][3] = cur3.w; a[3][4] = n3.x; a[3][5] = n3.y;
                    #pragma unroll
                    for (int e = 0; e < 2; ++e) {
                        int base = 2 * e;
                        float s00 = 0.f, s01 = 0.f, s10 = 0.f, s11 = 0.f;
                        #pragma unroll
                        for (int ky = 0; ky < 3; ++ky)
                        #pragma unroll
                        for (int kx = 0; kx < 3; ++kx) {
                            float w = wreg[ky * 3 + kx];
                            s00 = fmaf(a[ky][base + kx], w, s00);
                            s01 = fmaf(a[ky][base + kx + 1], w, s01);
                            s10 = fmaf(a[ky + 1][base + kx], w, s10);
                            s11 = fmaf(a[ky + 1][base + kx + 1], w, s11);
                        }
                        float m = fmaxf(fmaxf(s00, s01), fmaxf(s10, s11));
                        P[(py * 14 + 2 * k + e) * 33 + c] = fmaf(scv, m, shv);
                    }
                    cur0 = n0; cur1 = n1; cur2 = n2; cur3 = n3;
                }
            }
            __syncthreads();
            uint32_t* simg = s0b + (size_t)n * 4096;
            for (int i = t; i < 784; i += 256) {
                int pl = i >> 2, qd = i & 3;
                int iy = pl / 14, ix = pl - iy * 14;
                int yy = iy + 1, xx2 = ix + 1;
                int p = yy * 16 + xx2;
                int psw = (xx2 & 3) ^ (yy & 3);
                int g = qd ^ psw;
                const float* Pp = &P[pl * 33 + g * 8];
                uint32_t d[4];
                #pragma unroll
                for (int j = 0; j < 4; ++j) {
                    float h0 = Pp[2 * j], h1 = Pp[2 * j + 1];
                    uint32_t b0v = (h0 > 0.f) ? 0x3F80u : ((h0 < 0.f) ? 0xBF80u : 0u);
                    uint32_t b1v = (h1 > 0.f) ? 0x3F80u : ((h1 < 0.f) ? 0xBF80u : 0u);
                    d[j] = b0v | (b1v << 16);
                }
                uint4 v; v.x = d[0]; v.y = d[1]; v.z = d[2]; v.w = d[3];
                *(uint4*)(simg + p * 16 + qd * 4) = v;
            }
            if (t < 240) {
                int e = t >> 2, qd = t & 3;
                int yh, xh;
                if (e < 16)      { yh = 0;      xh = e; }
                else if (e < 32) { yh = 15;     xh = e - 16; }
                else if (e < 46) { yh = e - 31; xh = 0; }
                else             { yh = e - 45; xh = 15; }
                uint4 z; z.x = z.y = z.z = z.w = 0u;
                *(uint4*)(simg + (yh * 16 + xh) * 16 + qd * 4) = z;
            }
            if (t < 196) {
                int pw = t >> 2, oct = t & 3;
                int pyy = pw / 7, pxx = pw - pyy * 7;
                int b00 = ((2 * pyy) * 14 + 2 * pxx) * 33;
                int b01 = b00 + 33;
                int b10 = b00 + 14 * 33;
                int b11 = b10 + 33;
                float out[8];
                #pragma unroll
                for (int k = 0; k < 8; ++k) {
                    int cc = oct * 8 + k;
                    out[k] = fmaxf(fmaxf(P[b00 + cc], P[b01 + cc]),
                                   fmaxf(P[b10 + cc], P[b11 + cc]));
                }
                float4* hd = (float4*)(hp0 + ((size_t)n * 49 + pw) * 32 + oct * 8);
                float4 h0; h0.x = out[0]; h0.y = out[1]; h0.z = out[2]; h0.w = out[3];
                float4 h1; h1.x = out[4]; h1.y = out[5]; h1.z = out[6]; h1.w = out[7];
                hd[0] = h0; hd[1] = h1;
            }
            __syncthreads();
        }
    }
    grid.sync();

    // ---- Phase E: conv1 MFMA (4 image-pairs/block) ----
    {
        uint32_t* lds = (uint32_t*)smem;
        int q = lane >> 5, ncol = lane & 31;
        v8s wfr[18];
        #pragma unroll
        for (int f = 0; f < 18; ++f)
            wfr[f] = *(const v8s*)(w1f + (f * 2 + q) * 256 + ncol * 8);
        int img = wv >> 1, wh = wv & 1;
        int m = lane & 31;
        int quad = m & 3, pwl = m >> 2;
        int dy = quad >> 1, dx = quad & 1;
        for (int rep = 0; rep < 4; ++rep) {
            int pr = blk + rep * 512;
            int n0 = pr * 2;
            const uint4* gp = (const uint4*)(s0b + (size_t)n0 * 4096);
            uint4* lp = (uint4*)lds;
            #pragma unroll
            for (int i = 0; i < 8; ++i) lp[t + i * 256] = gp[t + i * 256];
            __syncthreads();
            int n = n0 + img;
            int ibase = img * 4096;
            double sAcc = 0.0, qAcc = 0.0;
            for (int tile = wh; tile < 7; tile += 2) {
                int pw = tile * 8 + pwl;
                int pwc = min(pw, 48);
                int py = pwc / 7, px = pwc - py * 7;
                int pbase = (2 * py + dy) * 16 + 2 * px + dx;
                v16f acc;
                #pragma unroll
                for (int i = 0; i < 16; ++i) acc[i] = 0.f;
                #pragma unroll
                for (int tp = 0; tp < 9; ++tp) {
                    int p = pbase + (tp / 3) * 16 + (tp % 3);
                    int psw = (p ^ (p >> 4)) & 3;
                    #pragma unroll
                    for (int kh = 0; kh < 2; ++kh) {
                        int g = kh * 2 + q;
                        int idx = ibase + p * 16 + ((g ^ psw) << 2);
                        v8s a = *(const v8s*)&lds[idx];
                        acc = __builtin_amdgcn_mfma_f32_32x32x16_bf16(a, wfr[tp * 2 + kh], acc, 0, 0, 0);
                    }
                }
                #pragma unroll
                for (int g4 = 0; g4 < 4; ++g4) {
                    float mx = fmaxf(fmaxf(acc[4 * g4], acc[4 * g4 + 1]),
                                     fmaxf(acc[4 * g4 + 2], acc[4 * g4 + 3]));
                    int pwo = tile * 8 + 2 * g4 + q;
                    if (pwo < 49) {
                        p1[((size_t)n * 49 + pwo) * 32 + ncol] = mx;
                        double v = (double)mx;
                        sAcc += v; qAcc += v * v;
                    }
                }
            }
            __syncthreads();
            double* red = (double*)smem;
            red[(wv * 2 + q) * 32 + ncol] = sAcc;
            red[256 + (wv * 2 + q) * 32 + ncol] = qAcc;
            __syncthreads();
            if (t < 32) {
                double S = 0.0, Q = 0.0;
                #pragma unroll
                for (int i = 0; i < 8; ++i) { S += red[i * 32 + t]; Q += red[256 + i * 32 + t]; }
                part1[(size_t)t * 2048 + pr] = S;
                part1[(size_t)32 * 2048 + (size_t)t * 2048 + pr] = Q;
            }
            __syncthreads();
        }
    }
    grid.sync();

    // ---- Phase F: finalize1 ----
    if (blk < 32) finalize_dev(part1, 2048, g1, b1, 1.0 / (4096.0 * 49.0), ss + 64, blk, t, smem);
    grid.sync();

    // ---- Phase G: bn1 (8 images/block) -> s1a (act-format, in s0b region) ----
    {
        float* H = (float*)smem;
        uint32_t* s1a = s0b;   // s0b dead after phase E
        for (int rep = 0; rep < 8; ++rep) {
            int n = blk + rep * 512;
            const float* P = p1 + (size_t)n * 1568;
            const float* Hp = hp0 + (size_t)n * 1568;
            for (int i = t; i < 1568; i += 256) {
                int c = i & 31;
                H[i] = fmaf(ss[64 + c], P[i], ss[96 + c]) + Hp[i];
            }
            __syncthreads();
            uint32_t* sp = s1a + (size_t)n * 1024;
            #pragma unroll
            for (int ii = 0; ii < 4; ++ii) {
                int i = t + ii * 256;
                int p = i >> 4, r = i & 15;
                int y = p >> 3, xq = p & 7;
                uint32_t d = 0u;
                if (y >= 1 && xq >= 1) {
                    int pix = (y - 1) * 7 + (xq - 1);
                    int sub = r & 3;
                    int g = (r >> 2) ^ (p & 3);
                    int c0 = ((g << 2) | sub) * 2;
                    float h0 = H[pix * 32 + c0];
                    float h1 = H[pix * 32 + c0 + 1];
                    uint32_t b0v = (h0 > 0.f) ? 0x3F80u : ((h0 < 0.f) ? 0xBF80u : 0u);
                    uint32_t b1v = (h1 > 0.f) ? 0x3F80u : ((h1 < 0.f) ? 0xBF80u : 0u);
                    d = b0v | (b1v << 16);
                }
                sp[i] = d;
            }
            for (int jj = t; jj < 288; jj += 256) {
                int c = jj / 9, pix = jj - c * 9;
                int r = pix / 3, qq = pix - r * 3;
                float a0 = H[((2 * r) * 7 + 2 * qq) * 32 + c];
                float a1 = H[((2 * r) * 7 + 2 * qq + 1) * 32 + c];
                float a2 = H[((2 * r + 1) * 7 + 2 * qq) * 32 + c];
                float a3 = H[((2 * r + 1) * 7 + 2 * qq + 1) * 32 + c];
                hp1[n * 288 + c * 9 + pix] = fmaxf(fmaxf(a0, a1), fmaxf(a2, a3));
            }
            __syncthreads();
        }
    }
    grid.sync();

    // ---- Phase H: conv2 MFMA (1 rep: 512 blocks x 8 images) ----
    {
        uint32_t* lds = (uint32_t*)smem;
        uint32_t* s1a = s0b;
        int n0 = blk * 8;
        const uint4* gp4 = (const uint4*)(s1a + (size_t)n0 * 1024);
        uint4* lp = (uint4*)lds;
        #pragma unroll
        for (int i = 0; i < 8; ++i) lp[t + i * 256] = gp4[t + i * 256];
        int q = lane >> 5, ncol = lane & 31;
        v8s wfr[18];
        #pragma unroll
        for (int f = 0; f < 18; ++f)
            wfr[f] = *(const v8s*)(w2f + (f * 2 + q) * 256 + ncol * 8);
        __syncthreads();
        int m = lane & 31;
        int quad = m & 3, pwl = m >> 2;
        int dy = quad >> 1, dx = quad & 1;
        double sAcc = 0.0, qAcc = 0.0;
        for (int tile = wv; tile < 9; tile += 4) {
            int pwg = tile * 8 + pwl;
            int img = pwg / 9, pwi = pwg - img * 9;
            int py = pwi / 3, px = pwi - py * 3;
            int pbase = (2 * py + dy) * 8 + 2 * px + dx;
            v16f acc;
            #pragma unroll
            for (int i = 0; i < 16; ++i) acc[i] = 0.f;
            #pragma unroll
            for (int tp = 0; tp < 9; ++tp) {
                int p = pbase + (tp / 3) * 8 + (tp % 3);
                int psw = p & 3;
                #pragma unroll
                for (int kh = 0; kh < 2; ++kh) {
                    int g = kh * 2 + q;
                    int idx = img * 1024 + p * 16 + ((g ^ psw) << 2);
                    v8s a = *(const v8s*)&lds[idx];
                    acc = __builtin_amdgcn_mfma_f32_32x32x16_bf16(a, wfr[tp * 2 + kh], acc, 0, 0, 0);
                }
            }
            #pragma unroll
            for (int g4 = 0; g4 < 4; ++g4) {
                float mx = fmaxf(fmaxf(acc[4 * g4], acc[4 * g4 + 1]),
                                 fmaxf(acc[4 * g4 + 2], acc[4 * g4 + 3]));
                int pwo = tile * 8 + 2 * g4 + q;
                int oimg = pwo / 9, opwi = pwo - oimg * 9;
                p2[(size_t)(n0 + oimg) * 288 + ncol * 9 + opwi] = mx;
                double v = (double)mx;
                sAcc += v; qAcc += v * v;
            }
        }
        __syncthreads();
        double* red = (double*)smem;
        red[(wv * 2 + q) * 32 + ncol] = sAcc;
        red[256 + (wv * 2 + q) * 32 + ncol] = qAcc;
        __syncthreads();
        if (t < 32) {
            double S = 0.0, Q = 0.0;
            #pragma unroll
            for (int i = 0; i < 8; ++i) { S += red[i * 32 + t]; Q += red[256 + i * 32 + t]; }
            part2[(size_t)t * 512 + blk] = S;
            part2[(size_t)32 * 512 + (size_t)t * 512 + blk] = Q;
        }
    }
    grid.sync();

    // ---- Phase I: finalize2 ----
    if (blk < 32) finalize_dev(part2, 512, g2, b2, 1.0 / (4096.0 * 9.0), ss + 128, blk, t, smem);
    grid.sync();

    // ---- Phase J: FC (8 images/block) ----
    {
        for (int rep = 0; rep < 2; ++rep) {
            int n = (blk * 2 + rep) * 4 + wv;
            int l = lane;
            float acc[10];
            #pragma unroll
            for (int k = 0; k < 10; ++k) acc[k] = 0.f;
            #pragma unroll
            for (int i = 0; i < 5; ++i) {
                int j = l + 64 * i;
                if (j < 288) {
                    int c = j / 9;
                    float h = fmaf(ss[128 + c], p2[n * 288 + j], ss[160 + c]) + hp1[n * 288 + j];
                    #pragma unroll
                    for (int k = 0; k < 10; ++k)
                        acc[k] = fmaf(h, fw[k * 288 + j], acc[k]);
                }
            }
            #pragma unroll
            for (int k = 0; k < 10; ++k) {
                float s = acc[k];
                #pragma unroll
                for (int o = 32; o > 0; o >>= 1) s += __shfl_down(s, o);
                if (l == 0) outv[n * 10 + k] = s + fb[k];
            }
        }
    }
}

// ===========================================================================
// Fallback multi-kernel pipeline (R15, passing at 211.7us) — used if the
// cooperative launch is rejected. Bit-identical outputs to k_mega.
// ===========================================================================
__global__ __launch_bounds__(448) void k_conv0s(const float* __restrict__ x,
                                                const float* __restrict__ w0,
                                                const float* __restrict__ w1,
                                                const float* __restrict__ w2,
                                                uint16_t* __restrict__ w1f,
                                                uint16_t* __restrict__ w2f,
                                                double* __restrict__ part0) {
    __shared__ float xs[960];
    __shared__ float wl[288];
    __shared__ double rs[448], rq[448];
    int n = blockIdx.x, t = threadIdx.x;
    if (n < 72 && t < 256) {
        int i = n * 256 + t;
        int ii = (i < 9216) ? i : i - 9216;
        const float* w = (i < 9216) ? w1 : w2;
        uint16_t* o = (i < 9216) ? w1f : w2f;
        int j = ii & 7, nn = (ii >> 3) & 31, q2 = (ii >> 8) & 1, kh = (ii >> 9) & 1, tp = ii >> 10;
        int cin = kh * 16 + q2 * 8 + j;
        float v = w[(nn * 32 + cin) * 9 + tp];
        o[ii] = (v > 0.f) ? 0x3F80 : ((v < 0.f) ? 0xBF80 : 0);
    }
    for (int i = t; i < 960; i += 448) xs[i] = 0.f;
    for (int i = t; i < 288; i += 448) wl[i] = w0[i];
    __syncthreads();
    for (int i = t; i < 784; i += 448) {
        int y = i / 28, xx = i - y * 28;
        xs[(y + 1) * 32 + xx + 1] = x[n * 784 + i];
    }
    __syncthreads();
    int c = t & 31, py = t >> 5;
    float wreg[9];
    #pragma unroll
    for (int i = 0; i < 9; ++i) wreg[i] = wl[c * 9 + i];
    const float4* X4 = (const float4*)xs;
    float4 cur0 = X4[(2 * py + 0) * 8];
    float4 cur1 = X4[(2 * py + 1) * 8];
    float4 cur2 = X4[(2 * py + 2) * 8];
    float4 cur3 = X4[(2 * py + 3) * 8];
    double s = 0.0, q = 0.0;
    #pragma unroll
    for (int k = 0; k < 7; ++k) {
        float4 n0 = X4[(2 * py + 0) * 8 + k + 1];
        float4 n1 = X4[(2 * py + 1) * 8 + k + 1];
        float4 n2 = X4[(2 * py + 2) * 8 + k + 1];
        float4 n3 = X4[(2 * py + 3) * 8 + k + 1];
        float a[4][6];
        a[0][0] = cur0.x; a[0][1] = cur0.y; a[0][2] = cur0.z; a[0][3] = cur0.w; a[0][4] = n0.x; a[0][5] = n0.y;
        a[1][0] = cur1.x; a[1][1] = cur1.y; a[1][2] = cur1.z; a[1][3] = cur1.w; a[1][4] = n1.x; a[1][5] = n1.y;
        a[2][0] = cur2.x; a[2][1] = cur2.y; a[2][2] = cur2.z; a[2][3] = cur2.w; a[2][4] = n2.x; a[2][5] = n2.y;
        a[3][0] = cur3.x; a[3][1] = cur3.y; a[3][2] = cur3.z; a[3][3] = cur3.w; a[3][4] = n3.x; a[3][5] = n3.y;
        #pragma unroll
        for (int e = 0; e < 2; ++e) {
            int base = 2 * e;
            float s00 = 0.f, s01 = 0.f, s10 = 0.f, s11 = 0.f;
            #pragma unroll
            for (int ky = 0; ky < 3; ++ky)
            #pragma unroll
            for (int kx = 0; kx < 3; ++kx) {
                float w = wreg[ky * 3 + kx];
                s00 = fmaf(a[ky][base + kx], w, s00);
                s01 = fmaf(a[ky][base + kx + 1], w, s01);
                s10 = fmaf(a[ky + 1][base + kx], w, s10);
                s11 = fmaf(a[ky + 1][base + kx + 1], w, s11);
            }
            float m = fmaxf(fmaxf(s00, s01), fmaxf(s10, s11));
            double v = (double)m;
            s += v; q += v * v;
        }
        cur0 = n0; cur1 = n1; cur2 = n2; cur3 = n3;
    }
    rs[c * 14 + py] = s; rq[c * 14 + py] = q;
    __syncthreads();
    if (t < 32) {
        double S = 0.0, Q = 0.0;
        #pragma unroll
        for (int i = 0; i < 14; ++i) { S += rs[t * 14 + i]; Q += rq[t * 14 + i]; }
        part0[(size_t)t * 4096 + n] = S;
        part0[(size_t)32 * 4096 + (size_t)t * 4096 + n] = Q;
    }
}

__global__ __launch_bounds__(256) void k_finalize(const double* __restrict__ part, int G,
                                                  const float* __restrict__ g,
                                                  const float* __restrict__ b,
                                                  double inv_count, float* __restrict__ ss) {
    __shared__ __align__(16) char smem[64];
    finalize_dev(part, G, g, b, inv_count, ss, blockIdx.x, threadIdx.x, smem);
}

__global__ __launch_bounds__(448) void k_bn0r(const float* __restrict__ x,
                                              const float* __restrict__ w0,
                                              const float* __restrict__ ss,
                                              uint32_t* __restrict__ s0b,
                                              float* __restrict__ hp0) {
    __shared__ float xs[960];
    __shared__ float wl[288];
    __shared__ float P[6468];
    int n = blockIdx.x, t = threadIdx.x;
    for (int i = t; i < 960; i += 448) xs[i] = 0.f;
    for (int i = t; i < 288; i += 448) wl[i] = w0[i];
    __syncthreads();
    for (int i = t; i < 784; i += 448) {
        int y = i / 28, xx = i - y * 28;
        xs[(y + 1) * 32 + xx + 1] = x[n * 784 + i];
    }
    __syncthreads();
    int c = t & 31, py = t >> 5;
    float wreg[9];
    #pragma unroll
    for (int i = 0; i < 9; ++i) wreg[i] = wl[c * 9 + i];
    float sc = ss[c], sh = ss[32 + c];
    const float4* X4 = (const float4*)xs;
    float4 cur0 = X4[(2 * py + 0) * 8];
    float4 cur1 = X4[(2 * py + 1) * 8];
    float4 cur2 = X4[(2 * py + 2) * 8];
    float4 cur3 = X4[(2 * py + 3) * 8];
    #pragma unroll
    for (int k = 0; k < 7; ++k) {
        float4 n0 = X4[(2 * py + 0) * 8 + k + 1];
        float4 n1 = X4[(2 * py + 1) * 8 + k + 1];
        float4 n2 = X4[(2 * py + 2) * 8 + k + 1];
        float4 n3 = X4[(2 * py + 3) * 8 + k + 1];
        float a[4][6];
        a[0][0] = cur0.x; a[0][1] = cur0.y; a[0][2] = cur0.z; a[0][3] = cur0.w; a[0][4] = n0.x; a[0][5] = n0.y;
        a[1][0] = cur1.x; a[1][1] = cur1.y; a[1][2] = cur1.z; a[1][3] = cur1.w; a[1][4] = n1.x; a[1][5] = n1.y;
        a[2][0] = cur2.x; a[2][1] = cur2.y; a[2][2] = cur2.z; a[2][3] = cur2.w; a[2][4] = n2.x; a[2][5] = n2.y;
        a[3][0] = cur3.x; a[3][1] = cur3.y; a[3][2] = cur3.z; a[3][3] = cur3.w; a[3][4] = n3.x; a[3][5] = n3.y;
        #pragma unroll
        for (int e = 0; e < 2; ++e) {
            int base = 2 * e;
            float s00 = 0.f, s01 = 0.f, s10 = 0.f, s11 = 0.f;
            #pragma unroll
            for (int ky = 0; ky < 3; ++ky)
            #pragma unroll
            for (int kx = 0; kx < 3; ++kx) {
                float w = wreg[ky * 3 + kx];
                s00 = fmaf(a[ky][base + kx], w, s00);
                s01 = fmaf(a[ky][base + kx + 1], w, s01);
                s10 = fmaf(a[ky + 1][base + kx], w, s10);
                s11 = fmaf(a[ky + 1][base + kx + 1], w, s11);
            }
            float m = fmaxf(fmaxf(s00, s01), fmaxf(s10, s11));
            P[(py * 14 + 2 * k + e) * 33 + c] = fmaf(sc, m, sh);
        }
        cur0 = n0; cur1 = n1; cur2 = n2; cur3 = n3;
    }
    __syncthreads();
    uint32_t* simg = s0b + (size_t)n * 4096;
    for (int i = t; i < 784; i += 448) {
        int pl = i >> 2, qd = i & 3;
        int iy = pl / 14, ix = pl - iy * 14;
        int yy = iy + 1, xx2 = ix + 1;
        int p = yy * 16 + xx2;
        int psw = (xx2 & 3) ^ (yy & 3);
        int g = qd ^ psw;
        const float* Pp = &P[pl * 33 + g * 8];
        uint32_t d[4];
        #pragma unroll
        for (int j = 0; j < 4; ++j) {
            float h0 = Pp[2 * j], h1 = Pp[2 * j + 1];
            uint32_t b0 = (h0 > 0.f) ? 0x3F80u : ((h0 < 0.f) ? 0xBF80u : 0u);
            uint32_t b1 = (h1 > 0.f) ? 0x3F80u : ((h1 < 0.f) ? 0xBF80u : 0u);
            d[j] = b0 | (b1 << 16);
        }
        uint4 v; v.x = d[0]; v.y = d[1]; v.z = d[2]; v.w = d[3];
        *(uint4*)(simg + p * 16 + qd * 4) = v;
    }
    if (t < 240) {
        int e = t >> 2, qd = t & 3;
        int yh, xh;
        if (e < 16)      { yh = 0;      xh = e; }
        else if (e < 32) { yh = 15;     xh = e - 16; }
        else if (e < 46) { yh = e - 31; xh = 0; }
        else             { yh = e - 45; xh = 15; }
        uint4 z; z.x = z.y = z.z = z.w = 0u;
        *(uint4*)(simg + (yh * 16 + xh) * 16 + qd * 4) = z;
    }
    if (t < 196) {
        int pw = t >> 2, oct = t & 3;
        int pyy = pw / 7, pxx = pw - pyy * 7;
        int b00 = ((2 * pyy) * 14 + 2 * pxx) * 33;
        int b01 = b00 + 33;
        int b10 = b00 + 14 * 33;
        int b11 = b10 + 33;
        float out[8];
        #pragma unroll
        for (int k = 0; k < 8; ++k) {
            int cc = oct * 8 + k;
            out[k] = fmaxf(fmaxf(P[b00 + cc], P[b01 + cc]),
                           fmaxf(P[b10 + cc], P[b11 + cc]));
        }
        float4* hd = (float4*)(hp0 + ((size_t)n * 49 + pw) * 32 + oct * 8);
        float4 h0; h0.x = out[0]; h0.y = out[1]; h0.z = out[2]; h0.w = out[3];
        float4 h1; h1.x = out[4]; h1.y = out[5]; h1.z = out[6]; h1.w = out[7];
        hd[0] = h0; hd[1] = h1;
    }
}

__global__ __launch_bounds__(256) void k_conv1m(const uint32_t* __restrict__ s0b,
                                                const uint16_t* __restrict__ w1f,
                                                float* __restrict__ p1,
                                                double* __restrict__ part1) {
    __shared__ uint32_t lds[8192];
    int t = threadIdx.x;
    int n0 = blockIdx.x * 2;
    const uint4* gp = (const uint4*)(s0b + (size_t)n0 * 4096);
    uint4* lp = (uint4*)lds;
    #pragma unroll
    for (int i = 0; i < 8; ++i) lp[t + i * 256] = gp[t + i * 256];
    int lane = t & 63, wv = t >> 6;
    int q = lane >> 5, ncol = lane & 31;
    v8s wfr[18];
    #pragma unroll
    for (int f = 0; f < 18; ++f)
        wfr[f] = *(const v8s*)(w1f + (f * 2 + q) * 256 + ncol * 8);
    __syncthreads();
    int img = wv >> 1, wh = wv & 1;
    int n = n0 + img;
    int ibase = img * 4096;
    int m = lane & 31;
    int quad = m & 3, pwl = m >> 2;
    int dy = quad >> 1, dx = quad & 1;
    double sAcc = 0.0, qAcc = 0.0;
    for (int tile = wh; tile < 7; tile += 2) {
        int pw = tile * 8 + pwl;
        int pwc = min(pw, 48);
        int py = pwc / 7, px = pwc - py * 7;
        int pbase = (2 * py + dy) * 16 + 2 * px + dx;
        v16f acc;
        #pragma unroll
        for (int i = 0; i < 16; ++i) acc[i] = 0.f;
        #pragma unroll
        for (int tp = 0; tp < 9; ++tp) {
            int p = pbase + (tp / 3) * 16 + (tp % 3);
            int psw = (p ^ (p >> 4)) & 3;
            #pragma unroll
            for (int kh = 0; kh < 2; ++kh) {
                int g = kh * 2 + q;
                int idx = ibase + p * 16 + ((g ^ psw) << 2);
                v8s a = *(const v8s*)&lds[idx];
                acc = __builtin_amdgcn_mfma_f32_32x32x16_bf16(a, wfr[tp * 2 + kh], acc, 0, 0, 0);
            }
        }
        #pragma unroll
        for (int g4 = 0; g4 < 4; ++g4) {
            float mx = fmaxf(fmaxf(acc[4 * g4], acc[4 * g4 + 1]),
                             fmaxf(acc[4 * g4 + 2], acc[4 * g4 + 3]));
            int pwo = tile * 8 + 2 * g4 + q;
            if (pwo < 49) {
                p1[((size_t)n * 49 + pwo) * 32 + ncol] = mx;
                double v = (double)mx;
                sAcc += v; qAcc += v * v;
            }
        }
    }
    __syncthreads();
    double* red = (double*)lds;
    red[(wv * 2 + q) * 32 + ncol] = sAcc;
    red[256 + (wv * 2 + q) * 32 + ncol] = qAcc;
    __syncthreads();
    if (t < 32) {
        double S = 0.0, Q = 0.0;
        #pragma unroll
        for (int i = 0; i < 8; ++i) { S += red[i * 32 + t]; Q += red[256 + i * 32 + t]; }
        part1[(size_t)t * 2048 + blockIdx.x] = S;
        part1[(size_t)32 * 2048 + (size_t)t * 2048 + blockIdx.x] = Q;
    }
}

__global__ __launch_bounds__(256) void k_bn1(const float* __restrict__ p1,
                                             const float* __restrict__ hp0,
                                             const float* __restrict__ ss,
                                             uint32_t* __restrict__ s1a,
                                             float* __restrict__ hp1) {
    __shared__ float H[1568];
    int n = blockIdx.x, t = threadIdx.x;
    const float* P = p1 + (size_t)n * 1568;
    const float* Hp = hp0 + (size_t)n * 1568;
    for (int i = t; i < 1568; i += 256) {
        int c = i & 31;
        H[i] = fmaf(ss[64 + c], P[i], ss[96 + c]) + Hp[i];
    }
    __syncthreads();
    uint32_t* sp = s1a + (size_t)n * 1024;
    #pragma unroll
    for (int ii = 0; ii < 4; ++ii) {
        int i = t + ii * 256;
        int p = i >> 4, r = i & 15;
        int y = p >> 3, xq = p & 7;
        uint32_t d = 0u;
        if (y >= 1 && xq >= 1) {
            int pix = (y - 1) * 7 + (xq - 1);
            int sub = r & 3;
            int g = (r >> 2) ^ (p & 3);
            int c0 = ((g << 2) | sub) * 2;
            float h0 = H[pix * 32 + c0];
            float h1 = H[pix * 32 + c0 + 1];
            uint32_t b0 = (h0 > 0.f) ? 0x3F80u : ((h0 < 0.f) ? 0xBF80u : 0u);
            uint32_t b1 = (h1 > 0.f) ? 0x3F80u : ((h1 < 0.f) ? 0xBF80u : 0u);
            d = b0 | (b1 << 16);
        }
        sp[i] = d;
    }
    for (int jj = t; jj < 288; jj += 256) {
        int c = jj / 9, pix = jj - c * 9;
        int r = pix / 3, qq = pix - r * 3;
        float a0 = H[((2 * r) * 7 + 2 * qq) * 32 + c];
        float a1 = H[((2 * r) * 7 + 2 * qq + 1) * 32 + c];
        float a2 = H[((2 * r + 1) * 7 + 2 * qq) * 32 + c];
        float a3 = H[((2 * r + 1) * 7 + 2 * qq + 1) * 32 + c];
        hp1[n * 288 + c * 9 + pix] = fmaxf(fmaxf(a0, a1), fmaxf(a2, a3));
    }
}

__global__ __launch_bounds__(256) void k_conv2m(const uint32_t* __restrict__ s1a,
                                                const uint16_t* __restrict__ w2f,
                                                float* __restrict__ p2,
                                                double* __restrict__ part2) {
    __shared__ uint32_t lds[8192];
    int t = threadIdx.x;
    int n0 = blockIdx.x * 8;
    const uint4* gp4 = (const uint4*)(s1a + (size_t)n0 * 1024);
    uint4* lp = (uint4*)lds;
    #pragma unroll
    for (int i = 0; i < 8; ++i) lp[t + i * 256] = gp4[t + i * 256];
    int lane = t & 63, wv = t >> 6;
    int q = lane >> 5, ncol = lane & 31;
    v8s wfr[18];
    #pragma unroll
    for (int f = 0; f < 18; ++f)
        wfr[f] = *(const v8s*)(w2f + (f * 2 + q) * 256 + ncol * 8);
    __syncthreads();
    int m = lane & 31;
    int quad = m & 3, pwl = m >> 2;
    int dy = quad >> 1, dx = quad & 1;
    double sAcc = 0.0, qAcc = 0.0;
    for (int tile = wv; tile < 9; tile += 4) {
        int pwg = tile * 8 + pwl;
        int img = pwg / 9, pwi = pwg - img * 9;
        int py = pwi / 3, px = pwi - py * 3;
        int pbase = (2 * py + dy) * 8 + 2 * px + dx;
        v16f acc;
        #pragma unroll
        for (int i = 0; i < 16; ++i) acc[i] = 0.f;
        #pragma unroll
        for (int tp = 0; tp < 9; ++tp) {
            int p = pbase + (tp / 3) * 8 + (tp % 3);
            int psw = p & 3;
            #pragma unroll
            for (int kh = 0; kh < 2; ++kh) {
                int g = kh * 2 + q;
                int idx = img * 1024 + p * 16 + ((g ^ psw) << 2);
                v8s a = *(const v8s*)&lds[idx];
                acc = __builtin_amdgcn_mfma_f32_32x32x16_bf16(a, wfr[tp * 2 + kh], acc, 0, 0, 0);
            }
        }
        #pragma unroll
        for (int g4 = 0; g4 < 4; ++g4) {
            float mx = fmaxf(fmaxf(acc[4 * g4], acc[4 * g4 + 1]),
                             fmaxf(acc[4 * g4 + 2], acc[4 * g4 + 3]));
            int pwo = tile * 8 + 2 * g4 + q;
            int oimg = pwo / 9, opwi = pwo - oimg * 9;
            p2[(size_t)(n0 + oimg) * 288 + ncol * 9 + opwi] = mx;
            double v = (double)mx;
            sAcc += v; qAcc += v * v;
        }
    }
    __syncthreads();
    double* red = (double*)lds;
    red[(wv * 2 + q) * 32 + ncol] = sAcc;
    red[256 + (wv * 2 + q) * 32 + ncol] = qAcc;
    __syncthreads();
    if (t < 32) {
        double S = 0.0, Q = 0.0;
        #pragma unroll
        for (int i = 0; i < 8; ++i) { S += red[i * 32 + t]; Q += red[256 + i * 32 + t]; }
        part2[(size_t)t * 512 + blockIdx.x] = S;
        part2[(size_t)32 * 512 + (size_t)t * 512 + blockIdx.x] = Q;
    }
}

__global__ __launch_bounds__(256) void k_fc(const float* __restrict__ p2,
                                            const float* __restrict__ hp1,
                                            const float* __restrict__ ss,
                                            const float* __restrict__ fw,
                                            const float* __restrict__ fb,
                                            float* __restrict__ outv) {
    int wv = threadIdx.x >> 6, l = threadIdx.x & 63;
    int n = blockIdx.x * 4 + wv;
    float acc[10];
    #pragma unroll
    for (int k = 0; k < 10; ++k) acc[k] = 0.f;
    #pragma unroll
    for (int i = 0; i < 5; ++i) {
        int j = l + 64 * i;
        if (j < 288) {
            int c = j / 9;
            float h = fmaf(ss[128 + c], p2[n * 288 + j], ss[160 + c]) + hp1[n * 288 + j];
            #pragma unroll
            for (int k = 0; k < 10; ++k)
                acc[k] = fmaf(h, fw[k * 288 + j], acc[k]);
        }
    }
    #pragma unroll
    for (int k = 0; k < 10; ++k) {
        float s = acc[k];
        #pragma unroll
        for (int o = 32; o > 0; o >>= 1) s += __shfl_down(s, o);
        if (l == 0) outv[n * 10 + k] = s + fb[k];
    }
}

// ---------------------------------------------------------------------------
// Workspace layout (bytes), ~154.2 MB (identical to R15):
//   ss @1024 | w1f @2048 | w2f @38912 | p1 @76800 | hp1 @32582656
//   p2 @37301248 | s0b/s1a @42019840 (64MB) | part0 @109128704
//   part1 @111225856 | part2 @112274432 | hp0 @128527360
// ---------------------------------------------------------------------------
extern "C" void kernel_launch(void* const* d_in, const int* in_sizes, int n_in,
                              void* d_out, int out_size, void* d_ws, size_t ws_size,
                              hipStream_t stream) {
    (void)in_sizes; (void)n_in; (void)out_size; (void)ws_size;
    const float* x  = (const float*)d_in[0];
    const float* w0 = (const float*)d_in[1];
    const float* g0 = (const float*)d_in[2];
    const float* b0 = (const float*)d_in[3];
    const float* w1 = (const float*)d_in[4];
    const float* g1 = (const float*)d_in[5];
    const float* b1 = (const float*)d_in[6];
    const float* w2 = (const float*)d_in[7];
    const float* g2 = (const float*)d_in[8];
    const float* b2 = (const float*)d_in[9];
    const float* fw = (const float*)d_in[10];
    const float* fb = (const float*)d_in[11];
    float* outv = (float*)d_out;
    char* ws = (char*)d_ws;

    float*     ss    = (float*)(ws + 1024);
    uint16_t*  w1f   = (uint16_t*)(ws + 2048);
    uint16_t*  w2f   = (uint16_t*)(ws + 38912);
    float*     p1    = (float*)(ws + 76800);
    float*     hp1   = (float*)(ws + 32582656);
    float*     p2    = (float*)(ws + 37301248);
    uint32_t*  s0b   = (uint32_t*)(ws + 42019840);
    double*    part0 = (double*)(ws + 109128704);
    double*    part1 = (double*)(ws + 111225856);
    double*    part2 = (double*)(ws + 112274432);
    float*     hp0   = (float*)(ws + 128527360);

    void* kargs[] = {
        (void*)&x, (void*)&w0, (void*)&w1, (void*)&w2,
        (void*)&g0, (void*)&b0, (void*)&g1, (void*)&b1,
        (void*)&g2, (void*)&b2, (void*)&fw, (void*)&fb,
        (void*)&w1f, (void*)&w2f, (void*)&ss, (void*)&p1,
        (void*)&hp1, (void*)&p2, (void*)&s0b,
        (void*)&part0, (void*)&part1, (void*)&part2, (void*)&hp0,
        (void*)&outv
    };
    hipError_t err = hipLaunchCooperativeKernel((void*)k_mega, dim3(512), dim3(256),
                                                kargs, 0, stream);
    if (err != hipSuccess) {
        // Fallback: bit-identical multi-kernel pipeline (R15).
        k_conv0s<<<BATCH, 448, 0, stream>>>(x, w0, w1, w2, w1f, w2f, part0);
        k_finalize<<<32, 256, 0, stream>>>(part0, 4096, g0, b0, 1.0 / (BATCH * 196.0), ss);
        k_bn0r<<<BATCH, 448, 0, stream>>>(x, w0, ss, s0b, hp0);
        k_conv1m<<<BATCH / 2, 256, 0, stream>>>(s0b, w1f, p1, part1);
        k_finalize<<<32, 256, 0, stream>>>(part1, 2048, g1, b1, 1.0 / (BATCH * 49.0), ss + 64);
        k_bn1<<<BATCH, 256, 0, stream>>>(p1, hp0, ss, s0b, hp1);
        k_conv2m<<<BATCH / 8, 256, 0, stream>>>(s0b, w2f, p2, part2);
        k_finalize<<<32, 256, 0, stream>>>(part2, 512, g2, b2, 1.0 / (BATCH * 9.0), ss + 128);
        k_fc<<<BATCH / 4, 256, 0, stream>>>(p2, hp1, ss, fw, fb, outv);
    }
}

// Round 17
// 210.465 us; speedup vs baseline: 3.3294x; 3.3294x over previous
//
#include <hip/hip_runtime.h>
#include <stdint.h>

#define BATCH 4096

typedef float v16f __attribute__((ext_vector_type(16)));
typedef short v8s  __attribute__((ext_vector_type(8)));

__device__ __forceinline__ int sgn8(float v) {
    return (v > 0.f) ? 1 : ((v < 0.f) ? -1 : 0);
}

// ---------------------------------------------------------------------------
// conv0s: stats-only conv0 (no p0 store) + FOLDED signw (blocks 0..71).
// 448 threads, c=t&31, py=t>>5. part0 layout [c*4096+n] (+32*4096 sq).
// FMA order canonical -- bn0r recomputes the same sequence bit-identically.
// NOTE (R13/R16 lessons): no device-scope fences / grid.sync anywhere --
// kernel boundaries are the only cheap cross-workgroup sync on CDNA4.
// ---------------------------------------------------------------------------
__global__ __launch_bounds__(448) void k_conv0s(const float* __restrict__ x,
                                                const float* __restrict__ w0,
                                                const float* __restrict__ w1,
                                                const float* __restrict__ w2,
                                                uint16_t* __restrict__ w1f,
                                                uint16_t* __restrict__ w2f,
                                                double* __restrict__ part0) {
    __shared__ float xs[960];   // 30 rows x 32 cols (zero halo)
    __shared__ float wl[288];
    __shared__ double rs[448], rq[448];   // [c*14+py]
    int n = blockIdx.x, t = threadIdx.x;

    if (n < 72 && t < 256) {
        int i = n * 256 + t;
        int ii = (i < 9216) ? i : i - 9216;
        const float* w = (i < 9216) ? w1 : w2;
        uint16_t* o = (i < 9216) ? w1f : w2f;
        int j = ii & 7, nn = (ii >> 3) & 31, q2 = (ii >> 8) & 1, kh = (ii >> 9) & 1, tp = ii >> 10;
        int cin = kh * 16 + q2 * 8 + j;
        float v = w[(nn * 32 + cin) * 9 + tp];
        o[ii] = (v > 0.f) ? 0x3F80 : ((v < 0.f) ? 0xBF80 : 0);
    }

    for (int i = t; i < 960; i += 448) xs[i] = 0.f;
    for (int i = t; i < 288; i += 448) wl[i] = w0[i];
    __syncthreads();
    for (int i = t; i < 784; i += 448) {
        int y = i / 28, xx = i - y * 28;
        xs[(y + 1) * 32 + xx + 1] = x[n * 784 + i];
    }
    __syncthreads();
    int c = t & 31, py = t >> 5;
    float wreg[9];
    #pragma unroll
    for (int i = 0; i < 9; ++i) wreg[i] = wl[c * 9 + i];
    const float4* X4 = (const float4*)xs;
    float4 cur0 = X4[(2 * py + 0) * 8];
    float4 cur1 = X4[(2 * py + 1) * 8];
    float4 cur2 = X4[(2 * py + 2) * 8];
    float4 cur3 = X4[(2 * py + 3) * 8];
    double s = 0.0, q = 0.0;
    #pragma unroll
    for (int k = 0; k < 7; ++k) {
        float4 n0 = X4[(2 * py + 0) * 8 + k + 1];
        float4 n1 = X4[(2 * py + 1) * 8 + k + 1];
        float4 n2 = X4[(2 * py + 2) * 8 + k + 1];
        float4 n3 = X4[(2 * py + 3) * 8 + k + 1];
        float a[4][6];
        a[0][0] = cur0.x; a[0][1] = cur0.y; a[0][2] = cur0.z; a[0][3] = cur0.w; a[0][4] = n0.x; a[0][5] = n0.y;
        a[1][0] = cur1.x; a[1][1] = cur1.y; a[1][2] = cur1.z; a[1][3] = cur1.w; a[1][4] = n1.x; a[1][5] = n1.y;
        a[2][0] = cur2.x; a[2][1] = cur2.y; a[2][2] = cur2.z; a[2][3] = cur2.w; a[2][4] = n2.x; a[2][5] = n2.y;
        a[3][0] = cur3.x; a[3][1] = cur3.y; a[3][2] = cur3.z; a[3][3] = cur3.w; a[3][4] = n3.x; a[3][5] = n3.y;
        #pragma unroll
        for (int e = 0; e < 2; ++e) {
            int base = 2 * e;
            float s00 = 0.f, s01 = 0.f, s10 = 0.f, s11 = 0.f;
            #pragma unroll
            for (int ky = 0; ky < 3; ++ky)
            #pragma unroll
            for (int kx = 0; kx < 3; ++kx) {
                float w = wreg[ky * 3 + kx];
                s00 = fmaf(a[ky][base + kx], w, s00);
                s01 = fmaf(a[ky][base + kx + 1], w, s01);
                s10 = fmaf(a[ky + 1][base + kx], w, s10);
                s11 = fmaf(a[ky + 1][base + kx + 1], w, s11);
            }
            float m = fmaxf(fmaxf(s00, s01), fmaxf(s10, s11));
            double v = (double)m;
            s += v; q += v * v;
        }
        cur0 = n0; cur1 = n1; cur2 = n2; cur3 = n3;
    }
    rs[c * 14 + py] = s; rq[c * 14 + py] = q;
    __syncthreads();
    if (t < 32) {
        double S = 0.0, Q = 0.0;
        #pragma unroll
        for (int i = 0; i < 14; ++i) { S += rs[t * 14 + i]; Q += rq[t * 14 + i]; }
        part0[(size_t)t * 4096 + n] = S;
        part0[(size_t)32 * 4096 + (size_t)t * 4096 + n] = Q;
    }
}

// ---------------------------------------------------------------------------
// finalize: grid(32) x 256 threads. Block = channel. Fixed-order reduction
// of G partials, layout part[c*G+i] / part[32G+c*G+i]; coalesced; double.
// ---------------------------------------------------------------------------
__global__ __launch_bounds__(256) void k_finalize(const double* __restrict__ part, int G,
                                                  const float* __restrict__ g,
                                                  const float* __restrict__ b,
                                                  double inv_count, float* __restrict__ ss) {
    int c = blockIdx.x, t = threadIdx.x;
    double s = 0.0, q = 0.0;
    for (int i = t; i < G; i += 256) {
        s += part[(size_t)c * G + i];
        q += part[(size_t)32 * G + (size_t)c * G + i];
    }
    #pragma unroll
    for (int o = 32; o > 0; o >>= 1) { s += __shfl_down(s, o); q += __shfl_down(q, o); }
    __shared__ double rs[4], rq[4];
    int w = t >> 6, l = t & 63;
    if (l == 0) { rs[w] = s; rq[w] = q; }
    __syncthreads();
    if (t == 0) {
        s = rs[0] + rs[1] + rs[2] + rs[3];
        q = rq[0] + rq[1] + rq[2] + rq[3];
        double mean = s * inv_count;
        double var = q * inv_count - mean * mean;
        double sc = (double)g[c] / sqrt(var + 1e-5);
        ss[c] = (float)sc;
        ss[32 + c] = (float)((double)b[c] - mean * sc);
    }
}

// ---------------------------------------------------------------------------
// bn0r: RECOMPUTES conv0 (bit-identical FMA order), applies BN, emits
// s0b (conv1m's pre-swizzled bf16 LDS image format, 16KB/img) + hp0 NHWC.
// ---------------------------------------------------------------------------
__global__ __launch_bounds__(448) void k_bn0r(const float* __restrict__ x,
                                              const float* __restrict__ w0,
                                              const float* __restrict__ ss,
                                              uint32_t* __restrict__ s0b,
                                              float* __restrict__ hp0) {
    __shared__ float xs[960];
    __shared__ float wl[288];
    __shared__ float P[6468];   // 196 x 33
    int n = blockIdx.x, t = threadIdx.x;
    for (int i = t; i < 960; i += 448) xs[i] = 0.f;
    for (int i = t; i < 288; i += 448) wl[i] = w0[i];
    __syncthreads();
    for (int i = t; i < 784; i += 448) {
        int y = i / 28, xx = i - y * 28;
        xs[(y + 1) * 32 + xx + 1] = x[n * 784 + i];
    }
    __syncthreads();
    int c = t & 31, py = t >> 5;
    float wreg[9];
    #pragma unroll
    for (int i = 0; i < 9; ++i) wreg[i] = wl[c * 9 + i];
    float sc = ss[c], sh = ss[32 + c];
    const float4* X4 = (const float4*)xs;
    float4 cur0 = X4[(2 * py + 0) * 8];
    float4 cur1 = X4[(2 * py + 1) * 8];
    float4 cur2 = X4[(2 * py + 2) * 8];
    float4 cur3 = X4[(2 * py + 3) * 8];
    #pragma unroll
    for (int k = 0; k < 7; ++k) {
        float4 n0 = X4[(2 * py + 0) * 8 + k + 1];
        float4 n1 = X4[(2 * py + 1) * 8 + k + 1];
        float4 n2 = X4[(2 * py + 2) * 8 + k + 1];
        float4 n3 = X4[(2 * py + 3) * 8 + k + 1];
        float a[4][6];
        a[0][0] = cur0.x; a[0][1] = cur0.y; a[0][2] = cur0.z; a[0][3] = cur0.w; a[0][4] = n0.x; a[0][5] = n0.y;
        a[1][0] = cur1.x; a[1][1] = cur1.y; a[1][2] = cur1.z; a[1][3] = cur1.w; a[1][4] = n1.x; a[1][5] = n1.y;
        a[2][0] = cur2.x; a[2][1] = cur2.y; a[2][2] = cur2.z; a[2][3] = cur2.w; a[2][4] = n2.x; a[2][5] = n2.y;
        a[3][0] = cur3.x; a[3][1] = cur3.y; a[3][2] = cur3.z; a[3][3] = cur3.w; a[3][4] = n3.x; a[3][5] = n3.y;
        #pragma unroll
        for (int e = 0; e < 2; ++e) {
            int base = 2 * e;
            float s00 = 0.f, s01 = 0.f, s10 = 0.f, s11 = 0.f;
            #pragma unroll
            for (int ky = 0; ky < 3; ++ky)
            #pragma unroll
            for (int kx = 0; kx < 3; ++kx) {
                float w = wreg[ky * 3 + kx];
                s00 = fmaf(a[ky][base + kx], w, s00);
                s01 = fmaf(a[ky][base + kx + 1], w, s01);
                s10 = fmaf(a[ky + 1][base + kx], w, s10);
                s11 = fmaf(a[ky + 1][base + kx + 1], w, s11);
            }
            float m = fmaxf(fmaxf(s00, s01), fmaxf(s10, s11));
            P[(py * 14 + 2 * k + e) * 33 + c] = fmaf(sc, m, sh);
        }
        cur0 = n0; cur1 = n1; cur2 = n2; cur3 = n3;
    }
    __syncthreads();
    uint32_t* simg = s0b + (size_t)n * 4096;
    for (int i = t; i < 784; i += 448) {
        int pl = i >> 2, qd = i & 3;
        int iy = pl / 14, ix = pl - iy * 14;
        int yy = iy + 1, xx2 = ix + 1;
        int p = yy * 16 + xx2;
        int psw = (xx2 & 3) ^ (yy & 3);
        int g = qd ^ psw;
        const float* Pp = &P[pl * 33 + g * 8];
        uint32_t d[4];
        #pragma unroll
        for (int j = 0; j < 4; ++j) {
            float h0 = Pp[2 * j], h1 = Pp[2 * j + 1];
            uint32_t b0 = (h0 > 0.f) ? 0x3F80u : ((h0 < 0.f) ? 0xBF80u : 0u);
            uint32_t b1 = (h1 > 0.f) ? 0x3F80u : ((h1 < 0.f) ? 0xBF80u : 0u);
            d[j] = b0 | (b1 << 16);
        }
        uint4 v; v.x = d[0]; v.y = d[1]; v.z = d[2]; v.w = d[3];
        *(uint4*)(simg + p * 16 + qd * 4) = v;
    }
    if (t < 240) {
        int e = t >> 2, qd = t & 3;
        int yh, xh;
        if (e < 16)      { yh = 0;      xh = e; }
        else if (e < 32) { yh = 15;     xh = e - 16; }
        else if (e < 46) { yh = e - 31; xh = 0; }
        else             { yh = e - 45; xh = 15; }
        uint4 z; z.x = z.y = z.z = z.w = 0u;
        *(uint4*)(simg + (yh * 16 + xh) * 16 + qd * 4) = z;
    }
    if (t < 196) {
        int pw = t >> 2, oct = t & 3;
        int pyy = pw / 7, pxx = pw - pyy * 7;
        int b00 = ((2 * pyy) * 14 + 2 * pxx) * 33;
        int b01 = b00 + 33;
        int b10 = b00 + 14 * 33;
        int b11 = b10 + 33;
        float out[8];
        #pragma unroll
        for (int k = 0; k < 8; ++k) {
            int cc = oct * 8 + k;
            out[k] = fmaxf(fmaxf(P[b00 + cc], P[b01 + cc]),
                           fmaxf(P[b10 + cc], P[b11 + cc]));
        }
        float4* hd = (float4*)(hp0 + ((size_t)n * 49 + pw) * 32 + oct * 8);
        float4 h0; h0.x = out[0]; h0.y = out[1]; h0.z = out[2]; h0.w = out[3];
        float4 h1; h1.x = out[4]; h1.y = out[5]; h1.z = out[6]; h1.w = out[7];
        hd[0] = h0; hd[1] = h1;
    }
}

// ---------------------------------------------------------------------------
// conv1m: bf16 MFMA implicit GEMM, 2 images/block. Staging = flat uint4 copy
// of bn0r's pre-swizzled blocks; swizzle psw=((p^(p>>4))&3). Fused stats,
// G=2048, part layout [c*2048+b] / +32*2048.
// ---------------------------------------------------------------------------
__global__ __launch_bounds__(256) void k_conv1m(const uint32_t* __restrict__ s0b,
                                                const uint16_t* __restrict__ w1f,
                                                float* __restrict__ p1,
                                                double* __restrict__ part1) {
    __shared__ uint32_t lds[8192];   // 32 KB
    int t = threadIdx.x;
    int n0 = blockIdx.x * 2;
    const uint4* gp = (const uint4*)(s0b + (size_t)n0 * 4096);
    uint4* lp = (uint4*)lds;
    #pragma unroll
    for (int i = 0; i < 8; ++i) lp[t + i * 256] = gp[t + i * 256];
    int lane = t & 63, wv = t >> 6;
    int q = lane >> 5, ncol = lane & 31;
    v8s wfr[18];
    #pragma unroll
    for (int f = 0; f < 18; ++f)
        wfr[f] = *(const v8s*)(w1f + (f * 2 + q) * 256 + ncol * 8);
    __syncthreads();
    int img = wv >> 1, wh = wv & 1;
    int n = n0 + img;
    int ibase = img * 4096;
    int m = lane & 31;
    int quad = m & 3, pwl = m >> 2;
    int dy = quad >> 1, dx = quad & 1;
    double sAcc = 0.0, qAcc = 0.0;
    for (int tile = wh; tile < 7; tile += 2) {
        int pw = tile * 8 + pwl;
        int pwc = min(pw, 48);
        int py = pwc / 7, px = pwc - py * 7;
        int pbase = (2 * py + dy) * 16 + 2 * px + dx;
        v16f acc;
        #pragma unroll
        for (int i = 0; i < 16; ++i) acc[i] = 0.f;
        #pragma unroll
        for (int tp = 0; tp < 9; ++tp) {
            int p = pbase + (tp / 3) * 16 + (tp % 3);
            int psw = (p ^ (p >> 4)) & 3;
            #pragma unroll
            for (int kh = 0; kh < 2; ++kh) {
                int g = kh * 2 + q;
                int idx = ibase + p * 16 + ((g ^ psw) << 2);
                v8s a = *(const v8s*)&lds[idx];
                acc = __builtin_amdgcn_mfma_f32_32x32x16_bf16(a, wfr[tp * 2 + kh], acc, 0, 0, 0);
            }
        }
        #pragma unroll
        for (int g4 = 0; g4 < 4; ++g4) {
            float mx = fmaxf(fmaxf(acc[4 * g4], acc[4 * g4 + 1]),
                             fmaxf(acc[4 * g4 + 2], acc[4 * g4 + 3]));
            int pwo = tile * 8 + 2 * g4 + q;
            if (pwo < 49) {
                p1[((size_t)n * 49 + pwo) * 32 + ncol] = mx;
                double v = (double)mx;
                sAcc += v; qAcc += v * v;
            }
        }
    }
    __syncthreads();
    double* red = (double*)lds;
    red[(wv * 2 + q) * 32 + ncol] = sAcc;
    red[256 + (wv * 2 + q) * 32 + ncol] = qAcc;
    __syncthreads();
    if (t < 32) {
        double S = 0.0, Q = 0.0;
        #pragma unroll
        for (int i = 0; i < 8; ++i) { S += red[i * 32 + t]; Q += red[256 + i * 32 + t]; }
        part1[(size_t)t * 2048 + blockIdx.x] = S;
        part1[(size_t)32 * 2048 + (size_t)t * 2048 + blockIdx.x] = Q;
    }
}

// ---------------------------------------------------------------------------
// bn1: block per image. h = bn1(p1) + hp0 (both NHWC) in LDS; emits
//  - s1a: conv2m's act-format packed bf16 signs (4KB/img, halo pre-zeroed),
//    built in PARALLEL by all 256 threads.
//  - hp1 NCHW [n][c][9] (for FC).
// ---------------------------------------------------------------------------
__global__ __launch_bounds__(256) void k_bn1(const float* __restrict__ p1,
                                             const float* __restrict__ hp0,
                                             const float* __restrict__ ss,
                                             uint32_t* __restrict__ s1a,
                                             float* __restrict__ hp1) {
    __shared__ float H[1568];
    int n = blockIdx.x, t = threadIdx.x;
    const float* P = p1 + (size_t)n * 1568;
    const float* Hp = hp0 + (size_t)n * 1568;
    for (int i = t; i < 1568; i += 256) {
        int c = i & 31;
        H[i] = fmaf(ss[64 + c], P[i], ss[96 + c]) + Hp[i];
    }
    __syncthreads();
    uint32_t* sp = s1a + (size_t)n * 1024;
    #pragma unroll
    for (int ii = 0; ii < 4; ++ii) {
        int i = t + ii * 256;
        int p = i >> 4, r = i & 15;
        int y = p >> 3, xq = p & 7;
        uint32_t d = 0u;
        if (y >= 1 && xq >= 1) {
            int pix = (y - 1) * 7 + (xq - 1);
            int sub = r & 3;
            int g = (r >> 2) ^ (p & 3);
            int c0 = ((g << 2) | sub) * 2;
            float h0 = H[pix * 32 + c0];
            float h1 = H[pix * 32 + c0 + 1];
            uint32_t b0 = (h0 > 0.f) ? 0x3F80u : ((h0 < 0.f) ? 0xBF80u : 0u);
            uint32_t b1 = (h1 > 0.f) ? 0x3F80u : ((h1 < 0.f) ? 0xBF80u : 0u);
            d = b0 | (b1 << 16);
        }
        sp[i] = d;
    }
    for (int jj = t; jj < 288; jj += 256) {
        int c = jj / 9, pix = jj - c * 9;
        int r = pix / 3, qq = pix - r * 3;
        float a0 = H[((2 * r) * 7 + 2 * qq) * 32 + c];
        float a1 = H[((2 * r) * 7 + 2 * qq + 1) * 32 + c];
        float a2 = H[((2 * r + 1) * 7 + 2 * qq) * 32 + c];
        float a3 = H[((2 * r + 1) * 7 + 2 * qq + 1) * 32 + c];
        hp1[n * 288 + c * 9 + pix] = fmaxf(fmaxf(a0, a1), fmaxf(a2, a3));
    }
}

// ---------------------------------------------------------------------------
// conv2m: bf16 MFMA implicit GEMM, 8 images/block. Staging = flat uint4 copy
// of bn1's pre-swizzled act blocks (halo already zeroed). Fused stats, G=512,
// part layout [c*512+b] / +32*512. p2 NCHW [n][32][9].
// ---------------------------------------------------------------------------
__global__ __launch_bounds__(256) void k_conv2m(const uint32_t* __restrict__ s1a,
                                                const uint16_t* __restrict__ w2f,
                                                float* __restrict__ p2,
                                                double* __restrict__ part2) {
    __shared__ uint32_t lds[8192];   // 32 KB
    int t = threadIdx.x;
    int n0 = blockIdx.x * 8;
    const uint4* gp4 = (const uint4*)(s1a + (size_t)n0 * 1024);
    uint4* lp = (uint4*)lds;
    #pragma unroll
    for (int i = 0; i < 8; ++i) lp[t + i * 256] = gp4[t + i * 256];
    int lane = t & 63, wv = t >> 6;
    int q = lane >> 5, ncol = lane & 31;
    v8s wfr[18];
    #pragma unroll
    for (int f = 0; f < 18; ++f)
        wfr[f] = *(const v8s*)(w2f + (f * 2 + q) * 256 + ncol * 8);
    __syncthreads();
    int m = lane & 31;
    int quad = m & 3, pwl = m >> 2;
    int dy = quad >> 1, dx = quad & 1;
    double sAcc = 0.0, qAcc = 0.0;
    for (int tile = wv; tile < 9; tile += 4) {
        int pwg = tile * 8 + pwl;
        int img = pwg / 9, pwi = pwg - img * 9;
        int py = pwi / 3, px = pwi - py * 3;
        int pbase = (2 * py + dy) * 8 + 2 * px + dx;
        v16f acc;
        #pragma unroll
        for (int i = 0; i < 16; ++i) acc[i] = 0.f;
        #pragma unroll
        for (int tp = 0; tp < 9; ++tp) {
            int p = pbase + (tp / 3) * 8 + (tp % 3);
            int psw = p & 3;
            #pragma unroll
            for (int kh = 0; kh < 2; ++kh) {
                int g = kh * 2 + q;
                int idx = img * 1024 + p * 16 + ((g ^ psw) << 2);
                v8s a = *(const v8s*)&lds[idx];
                acc = __builtin_amdgcn_mfma_f32_32x32x16_bf16(a, wfr[tp * 2 + kh], acc, 0, 0, 0);
            }
        }
        #pragma unroll
        for (int g4 = 0; g4 < 4; ++g4) {
            float mx = fmaxf(fmaxf(acc[4 * g4], acc[4 * g4 + 1]),
                             fmaxf(acc[4 * g4 + 2], acc[4 * g4 + 3]));
            int pwo = tile * 8 + 2 * g4 + q;
            int oimg = pwo / 9, opwi = pwo - oimg * 9;
            p2[(size_t)(n0 + oimg) * 288 + ncol * 9 + opwi] = mx;
            double v = (double)mx;
            sAcc += v; qAcc += v * v;
        }
    }
    __syncthreads();
    double* red = (double*)lds;
    red[(wv * 2 + q) * 32 + ncol] = sAcc;
    red[256 + (wv * 2 + q) * 32 + ncol] = qAcc;
    __syncthreads();
    if (t < 32) {
        double S = 0.0, Q = 0.0;
        #pragma unroll
        for (int i = 0; i < 8; ++i) { S += red[i * 32 + t]; Q += red[256 + i * 32 + t]; }
        part2[(size_t)t * 512 + blockIdx.x] = S;
        part2[(size_t)32 * 512 + (size_t)t * 512 + blockIdx.x] = Q;
    }
}

// ---------------------------------------------------------------------------
// FC: out[n,k] = sum_j (bn2(p2)+hp1)[n,j] * fw[k,j] + fb[k].  Wave per image.
// ---------------------------------------------------------------------------
__global__ __launch_bounds__(256) void k_fc(const float* __restrict__ p2,
                                            const float* __restrict__ hp1,
                                            const float* __restrict__ ss,
                                            const float* __restrict__ fw,
                                            const float* __restrict__ fb,
                                            float* __restrict__ outv) {
    int wv = threadIdx.x >> 6, l = threadIdx.x & 63;
    int n = blockIdx.x * 4 + wv;
    float acc[10];
    #pragma unroll
    for (int k = 0; k < 10; ++k) acc[k] = 0.f;
    #pragma unroll
    for (int i = 0; i < 5; ++i) {
        int j = l + 64 * i;
        if (j < 288) {
            int c = j / 9;
            float h = fmaf(ss[128 + c], p2[n * 288 + j], ss[160 + c]) + hp1[n * 288 + j];
            #pragma unroll
            for (int k = 0; k < 10; ++k)
                acc[k] = fmaf(h, fw[k * 288 + j], acc[k]);
        }
    }
    #pragma unroll
    for (int k = 0; k < 10; ++k) {
        float s = acc[k];
        #pragma unroll
        for (int o = 32; o > 0; o >>= 1) s += __shfl_down(s, o);
        if (l == 0) outv[n * 10 + k] = s + fb[k];
    }
}

// ---------------------------------------------------------------------------
// Workspace layout (bytes), ~154.2 MB:
//   ss @1024 | w1f @2048 | w2f @38912 | p1 @76800 | hp1 @32582656
//   p2 @37301248 | s0b/s1a @42019840 (64MB; s1a reuses after conv1m)
//   part0 @109128704 | part1 @111225856 | part2 @112274432 | hp0 @128527360
// 9 kernel nodes. Kernel-boundary ordering is the only cross-block sync
// (R13: per-block device fences cost ~300us; R16: grid.sync cost ~450us).
// ---------------------------------------------------------------------------
extern "C" void kernel_launch(void* const* d_in, const int* in_sizes, int n_in,
                              void* d_out, int out_size, void* d_ws, size_t ws_size,
                              hipStream_t stream) {
    (void)in_sizes; (void)n_in; (void)out_size; (void)ws_size;
    const float* x  = (const float*)d_in[0];
    const float* w0 = (const float*)d_in[1];
    const float* g0 = (const float*)d_in[2];
    const float* b0 = (const float*)d_in[3];
    const float* w1 = (const float*)d_in[4];
    const float* g1 = (const float*)d_in[5];
    const float* b1 = (const float*)d_in[6];
    const float* w2 = (const float*)d_in[7];
    const float* g2 = (const float*)d_in[8];
    const float* b2 = (const float*)d_in[9];
    const float* fw = (const float*)d_in[10];
    const float* fb = (const float*)d_in[11];
    float* outv = (float*)d_out;
    char* ws = (char*)d_ws;

    float*     ss    = (float*)(ws + 1024);
    uint16_t*  w1f   = (uint16_t*)(ws + 2048);
    uint16_t*  w2f   = (uint16_t*)(ws + 38912);
    float*     p1    = (float*)(ws + 76800);
    float*     hp1   = (float*)(ws + 32582656);
    float*     p2    = (float*)(ws + 37301248);
    uint32_t*  s0b   = (uint32_t*)(ws + 42019840);
    uint32_t*  s1a   = (uint32_t*)(ws + 42019840);   // reuses s0b region (dead after conv1m)
    double*    part0 = (double*)(ws + 109128704);
    double*    part1 = (double*)(ws + 111225856);
    double*    part2 = (double*)(ws + 112274432);
    float*     hp0   = (float*)(ws + 128527360);

    k_conv0s<<<BATCH, 448, 0, stream>>>(x, w0, w1, w2, w1f, w2f, part0);
    k_finalize<<<32, 256, 0, stream>>>(part0, 4096, g0, b0, 1.0 / (BATCH * 196.0), ss);
    k_bn0r<<<BATCH, 448, 0, stream>>>(x, w0, ss, s0b, hp0);

    k_conv1m<<<BATCH / 2, 256, 0, stream>>>(s0b, w1f, p1, part1);
    k_finalize<<<32, 256, 0, stream>>>(part1, 2048, g1, b1, 1.0 / (BATCH * 49.0), ss + 64);
    k_bn1<<<BATCH, 256, 0, stream>>>(p1, hp0, ss, s1a, hp1);

    k_conv2m<<<BATCH / 8, 256, 0, stream>>>(s1a, w2f, p2, part2);
    k_finalize<<<32, 256, 0, stream>>>(part2, 512, g2, b2, 1.0 / (BATCH * 9.0), ss + 128);

    k_fc<<<BATCH / 4, 256, 0, stream>>>(p2, hp1, ss, fw, fb, outv);
}